// Round 1
// baseline (420.391 us; speedup 1.0000x reference)
//
#include <hip/hip_runtime.h>

typedef unsigned short u16;
typedef unsigned int   u32;
typedef __attribute__((ext_vector_type(8))) short short8;
typedef __attribute__((ext_vector_type(4))) float f32x4;

#define NN   2024
#define NB   128
#define HID  128
#define MT   128
#define MTOT (NN*NB)

__device__ __forceinline__ float bf2f(u16 h){
  union { u32 u; float f; } c; c.u = ((u32)h) << 16; return c.f;
}
__device__ __forceinline__ u16 f2bf(float f){
  union { float f; u32 u; } c; c.f = f;
  return (u16)((c.u + 0x7fffu + ((c.u >> 16) & 1u)) >> 16);
}
__device__ __forceinline__ f32x4 mfma16(short8 a, short8 b, f32x4 c){
  return __builtin_amdgcn_mfma_f32_16x16x32_bf16(a, b, c, 0, 0, 0);
}

// 4-kstep GEMM over one K=128 chunk staged in LDS.
// A layout: lane holds A[row = base + (l&15)][k = ks*32 + (l>>4)*8 + i]
// B layout: lane holds B[k][col = 16j + (l&15)]  (Wb stored as [col][k])
// rows XOR-swizzled: byte_in_row ^= (row&7)<<4
__device__ __forceinline__ void gemm_chunk(f32x4 (&acc)[2][8], const u16* Ab,
                                           const u16* Wb, int l, int wv){
  const u32 swz   = ((u32)(l & 7)) << 4;
  const u32 klane = ((u32)(l >> 4)) << 4;
  const char* aB = (const char*)Ab + (u32)(32*wv + (l & 15)) * 256;
  const char* bB = (const char*)Wb + (u32)(l & 15) * 256;
#pragma unroll
  for (int ks = 0; ks < 4; ++ks){
    const u32 kbx = (((u32)ks << 6) + klane) ^ swz;
    short8 a0 = *(const short8*)(aB + kbx);
    short8 a1 = *(const short8*)(aB + 4096 + kbx);
#pragma unroll
    for (int j = 0; j < 8; ++j){
      short8 bf = *(const short8*)(bB + (u32)j*4096 + kbx);
      acc[0][j] = mfma16(a0, bf, acc[0][j]);
      acc[1][j] = mfma16(a1, bf, acc[1][j]);
    }
  }
}

// One GNN layer: out = LN(relu([h, agg(h)] @ W + b)) * g + beta, h rows = (b,n) flat.
// EMBED=1: h_in is synthesized on the fly from x (h0 = x*We + be).
template<int EMBED>
__global__ __launch_bounds__(256, 2)
void layer_k(const u16* __restrict__ hin, const float* __restrict__ x,
             const float* __restrict__ We, const float* __restrict__ be,
             const u16* __restrict__ Wt, const float* __restrict__ bias,
             const float* __restrict__ lng, const float* __restrict__ lnb,
             u16* __restrict__ hout)
{
  __shared__ __align__(16) u16 Ab[MT*128];
  __shared__ __align__(16) u16 Wb[128*128];
  const int t  = threadIdx.x;
  const int l  = t & 63;
  const int wv = t >> 6;
  const int m0 = blockIdx.x * MT;

  // staging coords: 2 threads per row, 8 chunks (of 8 bf16) each
  const int sR    = t >> 1;
  const int sm    = m0 + sR;
  const int cBase = (t & 1) * 8;
  const u32 sSwz  = ((u32)(sR & 7)) << 4;
  char* aRow = (char*)Ab + (u32)sR * 256;

  const int nd = sm % NN;   // node index within the graph
  const int v0 = (nd >= 45), v1 = (nd <= NN-46), v2 = (nd >= 1), v3 = (nd <= NN-2);
  const float inv = 1.0f / (float)(v0 + v1 + v2 + v3);

  // W staging: Wt is [128 cols][256 k] bf16 for this layer
  const int  wj   = t >> 1;
  const u32  wSwz = ((u32)(wj & 7)) << 4;
  const u16* wRow = Wt + (u32)wj * 256;
  char* wDst = (char*)Wb + (u32)wj * 256;

  f32x4 acc[2][8];
#pragma unroll
  for (int i = 0; i < 2; ++i)
#pragma unroll
    for (int j = 0; j < 8; ++j)
      acc[i][j] = (f32x4){0.f, 0.f, 0.f, 0.f};

  // ---------------- phase 0: stage A chunk0 (self) + W chunk0 ----------------
  if constexpr (EMBED) {
    const float xv = x[sm];
#pragma unroll
    for (int q = 0; q < 8; ++q){
      const int cL = cBase + q;
      short8 v;
#pragma unroll
      for (int i = 0; i < 8; ++i)
        v[i] = (short)f2bf(fmaf(xv, We[cL*8 + i], be[cL*8 + i]));
      *(short8*)(aRow + (((u32)cL << 4) ^ sSwz)) = v;
    }
  } else {
    const u16* hr = hin + (size_t)sm * HID;
#pragma unroll
    for (int q = 0; q < 8; ++q){
      const int cL = cBase + q;
      short8 v = *(const short8*)(hr + cL*8);
      *(short8*)(aRow + (((u32)cL << 4) ^ sSwz)) = v;
    }
  }
#pragma unroll
  for (int q = 0; q < 8; ++q){
    const int kc = cBase + q;
    short8 v = *(const short8*)(wRow + kc*8);
    *(short8*)(wDst + (((u32)kc << 4) ^ wSwz)) = v;
  }
  __syncthreads();
  gemm_chunk(acc, Ab, Wb, l, wv);
  __syncthreads();

  // ---------------- phase 1: stage A chunk1 (neighbor mean) + W chunk1 ----------------
  if constexpr (EMBED) {
    float sx = 0.f;
    if (v0) sx += x[sm - 45];
    if (v1) sx += x[sm + 45];
    if (v2) sx += x[sm - 1];
    if (v3) sx += x[sm + 1];
    sx *= inv;
#pragma unroll
    for (int q = 0; q < 8; ++q){
      const int cL = cBase + q;
      short8 v;
#pragma unroll
      for (int i = 0; i < 8; ++i)
        v[i] = (short)f2bf(fmaf(sx, We[cL*8 + i], be[cL*8 + i]));
      *(short8*)(aRow + (((u32)cL << 4) ^ sSwz)) = v;
    }
  } else {
    const u16* p0 = hin + (size_t)(sm - 45) * HID;
    const u16* p1 = hin + (size_t)(sm + 45) * HID;
    const u16* p2 = hin + (size_t)(sm - 1) * HID;
    const u16* p3 = hin + (size_t)(sm + 1) * HID;
#pragma unroll
    for (int q = 0; q < 8; ++q){
      const int cL = cBase + q;
      float s[8] = {0.f,0.f,0.f,0.f,0.f,0.f,0.f,0.f};
      if (v0){ short8 a = *(const short8*)(p0 + cL*8);
#pragma unroll
        for (int i = 0; i < 8; ++i) s[i] += bf2f((u16)a[i]); }
      if (v1){ short8 a = *(const short8*)(p1 + cL*8);
#pragma unroll
        for (int i = 0; i < 8; ++i) s[i] += bf2f((u16)a[i]); }
      if (v2){ short8 a = *(const short8*)(p2 + cL*8);
#pragma unroll
        for (int i = 0; i < 8; ++i) s[i] += bf2f((u16)a[i]); }
      if (v3){ short8 a = *(const short8*)(p3 + cL*8);
#pragma unroll
        for (int i = 0; i < 8; ++i) s[i] += bf2f((u16)a[i]); }
      short8 v;
#pragma unroll
      for (int i = 0; i < 8; ++i) v[i] = (short)f2bf(s[i] * inv);
      *(short8*)(aRow + (((u32)cL << 4) ^ sSwz)) = v;
    }
  }
#pragma unroll
  for (int q = 0; q < 8; ++q){
    const int kc = cBase + q;
    short8 v = *(const short8*)(wRow + 128 + kc*8);
    *(short8*)(wDst + (((u32)kc << 4) ^ wSwz)) = v;
  }
  __syncthreads();
  gemm_chunk(acc, Ab, Wb, l, wv);

  // ---------------- epilogue: bias + relu + LayerNorm + bf16 store ----------------
  const int cB = l & 15;
  const int rg = l >> 4;
  float bias8[8], g8[8], b8[8];
#pragma unroll
  for (int j = 0; j < 8; ++j){
    const int col = 16*j + cB;
    bias8[j] = bias[col]; g8[j] = lng[col]; b8[j] = lnb[col];
  }
#pragma unroll
  for (int i = 0; i < 2; ++i){
#pragma unroll
    for (int r = 0; r < 4; ++r){
      float s1 = 0.f, s2 = 0.f;
#pragma unroll
      for (int j = 0; j < 8; ++j){
        float y = fmaxf(acc[i][j][r] + bias8[j], 0.f);
        acc[i][j][r] = y;
        s1 += y; s2 += y*y;
      }
#pragma unroll
      for (int d = 1; d < 16; d <<= 1){
        s1 += __shfl_xor(s1, d);
        s2 += __shfl_xor(s2, d);
      }
      const float mu  = s1 * (1.f/128.f);
      const float var = s2 * (1.f/128.f) - mu*mu;
      const float rs  = rsqrtf(var + 1e-5f);
      const int m = m0 + 32*wv + 16*i + 4*rg + r;
      u16* orow = hout + (size_t)m * HID;
#pragma unroll
      for (int j = 0; j < 8; ++j){
        const float o = (acc[i][j][r] - mu) * rs * g8[j] + b8[j];
        orow[16*j + cB] = f2bf(o);
      }
    }
  }
}

// Transpose gnn_W [4][256k][128j] f32 -> Wt [4][128j][256k] bf16
__global__ void prep_k(const float* __restrict__ gw, u16* __restrict__ Wt){
  const int idx = blockIdx.x*256 + threadIdx.x;   // 131072 total
  const int lay = idx >> 15;
  const int r   = idx & 32767;
  const int j   = r >> 8;
  const int k   = r & 255;
  Wt[idx] = f2bf(gw[lay*32768 + k*128 + j]);
}

// graph_repr[b][f] = mean over n of h[b][n][f]
__global__ void mean_k(const u16* __restrict__ h, float* __restrict__ gr){
  __shared__ float red[16][16][8];
  const int b = blockIdx.x, t = threadIdx.x;
  const int cg = t & 15, q = t >> 4;
  float s[8] = {0.f,0.f,0.f,0.f,0.f,0.f,0.f,0.f};
  const u16* hb = h + (size_t)b * NN * HID;
  for (int n0 = q; n0 < NN; n0 += 16){
    short8 v = *(const short8*)(hb + (size_t)n0*HID + cg*8);
#pragma unroll
    for (int i = 0; i < 8; ++i) s[i] += bf2f((u16)v[i]);
  }
#pragma unroll
  for (int i = 0; i < 8; ++i) red[q][cg][i] = s[i];
  __syncthreads();
  if (t < 128){
    const int cc = t >> 3, i = t & 7;
    float a = 0.f;
#pragma unroll
    for (int qq = 0; qq < 16; ++qq) a += red[qq][cc][i];
    gr[b*HID + t] = a * (1.0f / 2024.0f);
  }
}

__global__ void head1_k(const float* __restrict__ gr, const float* __restrict__ W1,
                        const float* __restrict__ b1, float* __restrict__ hid){
  const int idx = blockIdx.x*256 + threadIdx.x;   // 16384
  const int b = idx >> 7, j = idx & 127;
  const float* g = gr + b*128;
  float a = b1[j];
  for (int k = 0; k < 128; ++k) a = fmaf(g[k], W1[k*128 + j], a);
  hid[idx] = fmaxf(a, 0.f);
}

__global__ void head2_k(const float* __restrict__ hid, const float* __restrict__ W2,
                        const float* __restrict__ b2, float* __restrict__ out){
  const int t = threadIdx.x;                      // 256 = 128 b x 2 o
  const int b = t >> 1, o = t & 1;
  const float* hh = hid + b*128;
  float a = b2[o];
  for (int k = 0; k < 128; ++k) a = fmaf(hh[k], W2[k*2 + o], a);
  out[t] = a;
}

extern "C" void kernel_launch(void* const* d_in, const int* in_sizes, int n_in,
                              void* d_out, int out_size, void* d_ws, size_t ws_size,
                              hipStream_t stream){
  const float* x  = (const float*)d_in[0];
  const float* We = (const float*)d_in[1];
  const float* be = (const float*)d_in[2];
  const float* gW = (const float*)d_in[3];
  const float* gb = (const float*)d_in[4];
  const float* lg = (const float*)d_in[5];
  const float* lb = (const float*)d_in[6];
  const float* W1 = (const float*)d_in[7];
  const float* b1 = (const float*)d_in[8];
  const float* W2 = (const float*)d_in[9];
  const float* b2 = (const float*)d_in[10];
  float* out = (float*)d_out;

  char* w = (char*)d_ws;
  const size_t HB = (size_t)MTOT * HID * 2;       // 66,322,432 B per h buffer
  u16*   hA  = (u16*)w;
  u16*   hB  = (u16*)(w + HB);
  u16*   Wt  = (u16*)(w + 2*HB);                  // 262,144 B
  float* gr  = (float*)(w + 2*HB + 262144);       // 65,536 B
  float* hid = (float*)(w + 2*HB + 262144 + 65536);

  prep_k<<<512, 256, 0, stream>>>(gW, Wt);
  layer_k<1><<<MTOT/MT, 256, 0, stream>>>(nullptr, x, We, be, Wt,
                                          gb, lg, lb, hA);
  layer_k<0><<<MTOT/MT, 256, 0, stream>>>(hA, nullptr, nullptr, nullptr, Wt + 32768,
                                          gb + 128, lg + 128, lb + 128, hB);
  layer_k<0><<<MTOT/MT, 256, 0, stream>>>(hB, nullptr, nullptr, nullptr, Wt + 65536,
                                          gb + 256, lg + 256, lb + 256, hA);
  layer_k<0><<<MTOT/MT, 256, 0, stream>>>(hA, nullptr, nullptr, nullptr, Wt + 98304,
                                          gb + 384, lg + 384, lb + 384, hB);
  mean_k<<<NB, 256, 0, stream>>>(hB, gr);
  head1_k<<<64, 256, 0, stream>>>(gr, W1, b1, hid);
  head2_k<<<1, 256, 0, stream>>>(hid, W2, b2, out);
}

// Round 2
// 309.337 us; speedup vs baseline: 1.3590x; 1.3590x over previous
//
#include <hip/hip_runtime.h>

typedef unsigned short u16;
typedef unsigned int   u32;
typedef __attribute__((ext_vector_type(8))) short short8;
typedef __attribute__((ext_vector_type(4))) float f32x4;

#define NN   2024
#define NB   128
#define HID  128
#define MT   128
#define MTOT (NN*NB)

__device__ __forceinline__ float bf2f(u16 h){ union{u32 u; float f;}c; c.u=((u32)h)<<16; return c.f; }
__device__ __forceinline__ u16 f2bf(float f){ union{float f; u32 u;}c; c.f=f; return (u16)((c.u+0x7fffu+((c.u>>16)&1u))>>16); }
__device__ __forceinline__ f32x4 mfma16(short8 a, short8 b, f32x4 c){ return __builtin_amdgcn_mfma_f32_16x16x32_bf16(a,b,c,0,0,0); }
__device__ __forceinline__ void glds16(const void* g, void* l){
  __builtin_amdgcn_global_load_lds((const __attribute__((address_space(1))) void*)g,
                                   (__attribute__((address_space(3))) void*)l, 16, 0, 0);
}

// GEMM over one K=128 chunk. Wave tile 32 rows x 64 cols.
// A layout: lane holds A[row = 32*wr + (l&15) + 16m][k = ks*32 + (l>>4)*8 + i]
// B layout: lane holds B[k][col = 64*wc + 16j + (l&15)]  (Wb stored [col][k])
// LDS rows XOR-swizzled: byte_in_row ^= (row&7)<<4
__device__ __forceinline__ void gemm_chunk(f32x4 (&acc)[2][4], const u16* Ab,
                                           const u16* Wb, int l, int wr, int wc){
  const u32 swz   = ((u32)(l & 7)) << 4;
  const u32 klane = ((u32)(l >> 4)) << 4;
  const char* aB = (const char*)Ab + (u32)(32*wr + (l & 15)) * 256;
  const char* bB = (const char*)Wb + (u32)(64*wc + (l & 15)) * 256;
#pragma unroll
  for (int ks = 0; ks < 4; ++ks){
    const u32 kbx = (((u32)ks << 6) + klane) ^ swz;
    short8 a0 = *(const short8*)(aB + kbx);
    short8 a1 = *(const short8*)(aB + 4096 + kbx);
#pragma unroll
    for (int j = 0; j < 4; ++j){
      short8 bf = *(const short8*)(bB + (u32)j*4096 + kbx);
      acc[0][j] = mfma16(a0, bf, acc[0][j]);
      acc[1][j] = mfma16(a1, bf, acc[1][j]);
    }
  }
}

// One GNN layer: out = LN(relu([h, agg(h)] @ W + b)) * g + beta.
// 512 threads, 8 waves in 4(row) x 2(col) grid. EMBED=1 synthesizes h0 from x.
template<int EMBED>
__global__ __launch_bounds__(512, 4)
void layer_k(const u16* __restrict__ hin, const float* __restrict__ x,
             const float* __restrict__ We, const float* __restrict__ be,
             const u16* __restrict__ Wt, const float* __restrict__ bias,
             const float* __restrict__ lng, const float* __restrict__ lnb,
             u16* __restrict__ hout)
{
  __shared__ __align__(16) u16 Ab[MT*128];     // 32 KB
  __shared__ __align__(16) u16 Wb[128*128];    // 32 KB
  const int t  = threadIdx.x;
  const int l  = t & 63;
  const int wv = t >> 6;       // 0..7
  const int wr = wv >> 1;      // row-wave 0..3
  const int wc = wv & 1;       // col-wave 0..1
  const int m0 = blockIdx.x * MT;

  // glds slot coords
  const int gl16 = l >> 4, gcl = l & 15;

  // agg/synth staging coords: 4 threads per row, 4 chunks each
  const int sR = t >> 2;       // 0..127
  const int cq = t & 3;
  const int c0 = cq * 4;
  const int sm = m0 + sR;
  const u32 sSwz = ((u32)(sR & 7)) << 4;
  char* aRow = (char*)Ab + (u32)sR * 256;

  const int nd = sm % NN;
  const int v0 = (nd >= 45), v1 = (nd <= NN-46), v2 = (nd >= 1), v3 = (nd <= NN-2);
  const float inv = 1.0f / (float)(v0 + v1 + v2 + v3);

  f32x4 acc[2][4];
#pragma unroll
  for (int m = 0; m < 2; ++m)
#pragma unroll
    for (int j = 0; j < 4; ++j)
      acc[m][j] = (f32x4){0.f,0.f,0.f,0.f};

  // ---------------- stage 0: A self + W chunk0 (+ prefetch n0,n1) ----------------
  if constexpr (EMBED) {
    const float xv = x[sm];
#pragma unroll
    for (int q = 0; q < 4; ++q){
      const int c = c0 + q;
      short8 v;
#pragma unroll
      for (int i = 0; i < 8; ++i) v[i] = (short)f2bf(fmaf(xv, We[c*8+i], be[c*8+i]));
      *(short8*)(aRow + (((u32)c << 4) ^ sSwz)) = v;
    }
  } else {
#pragma unroll
    for (int i = 0; i < 4; ++i){
      const int r  = wv*16 + i*4 + gl16;
      const int cs = gcl ^ (r & 7);
      glds16(hin + (size_t)(m0 + r)*HID + cs*8, (char*)Ab + (u32)(wv*4 + i)*1024);
    }
  }
#pragma unroll
  for (int i = 0; i < 4; ++i){
    const int col = wv*16 + i*4 + gl16;
    const int cs  = gcl ^ (col & 7);
    glds16(Wt + (u32)col*256 + cs*8, (char*)Wb + (u32)(wv*4 + i)*1024);
  }

  short8 gA[4], gB[4];
  if constexpr (!EMBED) {
    const u16* p0 = hin + (size_t)(v0 ? sm-45 : sm) * HID;
    const u16* p1 = hin + (size_t)(v1 ? sm+45 : sm) * HID;
#pragma unroll
    for (int q = 0; q < 4; ++q){
      gA[q] = *(const short8*)(p0 + (c0+q)*8);
      gB[q] = *(const short8*)(p1 + (c0+q)*8);
    }
  }
  __syncthreads();

  gemm_chunk(acc, Ab, Wb, l, wr, wc);            // chunk 0 (self)

  // ---------------- between gemms: finish agg (n2,n3 async) ----------------
  float sq[4][8];
  short8 gC[4], gD[4];
  float mx = 0.f;
  if constexpr (!EMBED) {
    const u16* p2 = hin + (size_t)(v2 ? sm-1 : sm) * HID;
    const u16* p3 = hin + (size_t)(v3 ? sm+1 : sm) * HID;
#pragma unroll
    for (int q = 0; q < 4; ++q){
      gC[q] = *(const short8*)(p2 + (c0+q)*8);
      gD[q] = *(const short8*)(p3 + (c0+q)*8);
    }
    const float f0 = (float)v0, f1 = (float)v1;
#pragma unroll
    for (int q = 0; q < 4; ++q)
#pragma unroll
      for (int i = 0; i < 8; ++i)
        sq[q][i] = f0*bf2f((u16)gA[q][i]) + f1*bf2f((u16)gB[q][i]);
  } else {
    if (v0) mx += x[sm-45];
    if (v1) mx += x[sm+45];
    if (v2) mx += x[sm-1];
    if (v3) mx += x[sm+1];
    mx *= inv;
  }
  __syncthreads();                                // all waves done reading chunk0 LDS

  if constexpr (!EMBED) {
    const float f2 = (float)v2, f3 = (float)v3;
#pragma unroll
    for (int q = 0; q < 4; ++q){
      short8 v;
#pragma unroll
      for (int i = 0; i < 8; ++i){
        const float s = (sq[q][i] + f2*bf2f((u16)gC[q][i]) + f3*bf2f((u16)gD[q][i])) * inv;
        v[i] = (short)f2bf(s);
      }
      *(short8*)(aRow + (((u32)(c0+q) << 4) ^ sSwz)) = v;
    }
  } else {
#pragma unroll
    for (int q = 0; q < 4; ++q){
      const int c = c0 + q;
      short8 v;
#pragma unroll
      for (int i = 0; i < 8; ++i) v[i] = (short)f2bf(fmaf(mx, We[c*8+i], be[c*8+i]));
      *(short8*)(aRow + (((u32)c << 4) ^ sSwz)) = v;
    }
  }
#pragma unroll
  for (int i = 0; i < 4; ++i){
    const int col = wv*16 + i*4 + gl16;
    const int cs  = gcl ^ (col & 7);
    glds16(Wt + (u32)col*256 + 128 + cs*8, (char*)Wb + (u32)(wv*4 + i)*1024);
  }
  __syncthreads();

  gemm_chunk(acc, Ab, Wb, l, wr, wc);            // chunk 1 (agg)
  __syncthreads();                                // Ab free -> overlay LN reduce buffer

  // ---------------- epilogue: bias+relu+LN (cross-col-wave via LDS) ----------------
  float2* red = (float2*)Ab;                      // [128 rows][2 col-waves]
  const int cB = l & 15, rg = l >> 4;
  float bias4[4], g4[4], be4[4];
#pragma unroll
  for (int j = 0; j < 4; ++j){
    const int col = 64*wc + 16*j + cB;
    bias4[j] = bias[col]; g4[j] = lng[col]; be4[j] = lnb[col];
  }
#pragma unroll
  for (int m = 0; m < 2; ++m){
#pragma unroll
    for (int r = 0; r < 4; ++r){
      float p1 = 0.f, p2 = 0.f;
#pragma unroll
      for (int j = 0; j < 4; ++j){
        float y = fmaxf(acc[m][j][r] + bias4[j], 0.f);
        acc[m][j][r] = y;
        p1 += y; p2 += y*y;
      }
#pragma unroll
      for (int d = 1; d < 16; d <<= 1){
        p1 += __shfl_xor(p1, d);
        p2 += __shfl_xor(p2, d);
      }
      if (cB == 0){
        const int row = 32*wr + 16*m + 4*rg + r;
        red[row*2 + wc] = make_float2(p1, p2);
      }
    }
  }
  __syncthreads();
#pragma unroll
  for (int m = 0; m < 2; ++m){
#pragma unroll
    for (int r = 0; r < 4; ++r){
      const int row = 32*wr + 16*m + 4*rg + r;
      const float2 pa = red[row*2], pb = red[row*2 + 1];
      const float s1 = pa.x + pb.x, s2 = pa.y + pb.y;
      const float mu  = s1 * (1.f/128.f);
      const float var = s2 * (1.f/128.f) - mu*mu;
      const float rs  = rsqrtf(var + 1e-5f);
      u16* orow = hout + (size_t)(m0 + row) * HID;
#pragma unroll
      for (int j = 0; j < 4; ++j){
        const float o = (acc[m][j][r] - mu) * rs * g4[j] + be4[j];
        orow[64*wc + 16*j + cB] = f2bf(o);
      }
    }
  }
}

// Transpose gnn_W [4][256k][128j] f32 -> Wt [4][128j][256k] bf16
__global__ void prep_k(const float* __restrict__ gw, u16* __restrict__ Wt){
  const int idx = blockIdx.x*256 + threadIdx.x;   // 131072
  const int lay = idx >> 15;
  const int r   = idx & 32767;
  const int j   = r >> 8;
  const int k   = r & 255;
  Wt[idx] = f2bf(gw[lay*32768 + k*128 + j]);
}

// stage 1 of graph mean: 8 partials per batch image
__global__ void mean1_k(const u16* __restrict__ h, float* __restrict__ partial){
  __shared__ float red[16][16][8];
  const int blk = blockIdx.x;                     // 1024 = 128 b x 8 s
  const int b = blk >> 3, s = blk & 7;
  const int t = threadIdx.x;
  const int cg = t & 15, q = t >> 4;
  const int nbeg = s*253, nend = nbeg + 253;
  float a[8] = {0.f,0.f,0.f,0.f,0.f,0.f,0.f,0.f};
  const u16* hb = h + (size_t)b * NN * HID;
  for (int n = nbeg + q; n < nend; n += 16){
    short8 v = *(const short8*)(hb + (size_t)n*HID + cg*8);
#pragma unroll
    for (int i = 0; i < 8; ++i) a[i] += bf2f((u16)v[i]);
  }
#pragma unroll
  for (int i = 0; i < 8; ++i) red[q][cg][i] = a[i];
  __syncthreads();
  if (t < 128){
    const int cc = t >> 3, i = t & 7;
    float v = 0.f;
#pragma unroll
    for (int qq = 0; qq < 16; ++qq) v += red[qq][cc][i];
    partial[((size_t)b*8 + s)*128 + t] = v;
  }
}

__global__ void mean2_k(const float* __restrict__ partial, float* __restrict__ gr){
  const int idx = blockIdx.x*256 + threadIdx.x;   // 16384
  const int b = idx >> 7, c = idx & 127;
  float a = 0.f;
#pragma unroll
  for (int s = 0; s < 8; ++s) a += partial[((size_t)b*8 + s)*128 + c];
  gr[idx] = a * (1.0f / 2024.0f);
}

__global__ void head1_k(const float* __restrict__ gr, const float* __restrict__ W1,
                        const float* __restrict__ b1, float* __restrict__ hid){
  const int idx = blockIdx.x*256 + threadIdx.x;   // 16384
  const int b = idx >> 7, j = idx & 127;
  const float* g = gr + b*128;
  float a = b1[j];
  for (int k = 0; k < 128; ++k) a = fmaf(g[k], W1[k*128 + j], a);
  hid[idx] = fmaxf(a, 0.f);
}

__global__ void head2_k(const float* __restrict__ hid, const float* __restrict__ W2,
                        const float* __restrict__ b2, float* __restrict__ out){
  const int t = threadIdx.x;                      // 256 = 128 b x 2 o
  const int b = t >> 1, o = t & 1;
  const float* hh = hid + b*128;
  float a = b2[o];
  for (int k = 0; k < 128; ++k) a = fmaf(hh[k], W2[k*2 + o], a);
  out[t] = a;
}

extern "C" void kernel_launch(void* const* d_in, const int* in_sizes, int n_in,
                              void* d_out, int out_size, void* d_ws, size_t ws_size,
                              hipStream_t stream){
  const float* x  = (const float*)d_in[0];
  const float* We = (const float*)d_in[1];
  const float* be = (const float*)d_in[2];
  const float* gW = (const float*)d_in[3];
  const float* gb = (const float*)d_in[4];
  const float* lg = (const float*)d_in[5];
  const float* lb = (const float*)d_in[6];
  const float* W1 = (const float*)d_in[7];
  const float* b1 = (const float*)d_in[8];
  const float* W2 = (const float*)d_in[9];
  const float* b2 = (const float*)d_in[10];
  float* out = (float*)d_out;

  char* w = (char*)d_ws;
  const size_t HB = (size_t)MTOT * HID * 2;       // 66,322,432 B per h buffer
  u16*   hA  = (u16*)w;
  u16*   hB  = (u16*)(w + HB);
  u16*   Wt  = (u16*)(w + 2*HB);                  // 262,144 B
  float* gr  = (float*)(w + 2*HB + 262144);       // 65,536 B
  float* hid = (float*)(w + 2*HB + 262144 + 65536);
  float* partial = (float*)w;                     // overlays hA (dead after L3)

  prep_k<<<512, 256, 0, stream>>>(gW, Wt);
  layer_k<1><<<MTOT/MT, 512, 0, stream>>>(nullptr, x, We, be, Wt,
                                          gb, lg, lb, hA);
  layer_k<0><<<MTOT/MT, 512, 0, stream>>>(hA, nullptr, nullptr, nullptr, Wt + 32768,
                                          gb + 128, lg + 128, lb + 128, hB);
  layer_k<0><<<MTOT/MT, 512, 0, stream>>>(hB, nullptr, nullptr, nullptr, Wt + 65536,
                                          gb + 256, lg + 256, lb + 256, hA);
  layer_k<0><<<MTOT/MT, 512, 0, stream>>>(hA, nullptr, nullptr, nullptr, Wt + 98304,
                                          gb + 384, lg + 384, lb + 384, hB);
  mean1_k<<<NB*8, 256, 0, stream>>>(hB, partial);
  mean2_k<<<64, 256, 0, stream>>>(partial, gr);
  head1_k<<<64, 256, 0, stream>>>(gr, W1, b1, hid);
  head2_k<<<1, 256, 0, stream>>>(hid, W2, b2, out);
}